// Round 12
// baseline (324.985 us; speedup 1.0000x reference)
//
#include <hip/hip_runtime.h>
#include <cstddef>
#include <cstdint>
#include <type_traits>

#define N_NODES 20000
#define NPAD 20096            // multiple of 128 for MFMA row tiles
#define E0_EDGES 160000
#define E_TOT (E0_EDGES + N_NODES)
#define CAP 64                // max in-degree slots (Poisson(9); P(>=64) ~ 0)

typedef __bf16 bf16x8 __attribute__((ext_vector_type(8)));
typedef float f32x4 __attribute__((ext_vector_type(4)));

__device__ __forceinline__ ushort f2bf(float f) {
  uint32_t u = __float_as_uint(f);
  return (ushort)((u + 0x7FFFu + ((u >> 16) & 1u)) >> 16);  // RNE
}
__device__ __forceinline__ float bf2f(ushort h) {
  return __uint_as_float((uint32_t)h << 16);
}

// chunk swizzle for 64B LDS rows
__device__ __forceinline__ int SW(int r) { return ((r >> 1) & 3) ^ ((r >> 3) & 1); }

// async global->LDS, 16B/lane; LDS dest = wave-uniform base + lane*16
#define GLOAD16(g, l)                                                         \
  __builtin_amdgcn_global_load_lds(                                           \
      (const __attribute__((address_space(1))) void*)(uintptr_t)(g),          \
      (__attribute__((address_space(3))) void*)(uint32_t)(uintptr_t)(l),      \
      16, 0, 0)

// ======================= CSR via fixed-stride slots ==========================

__global__ void fill_csr_kernel(const int* __restrict__ ei, int* __restrict__ cnt,
                                int* __restrict__ slots) {
  int e = blockIdx.x * blockDim.x + threadIdx.x;
  if (e >= E_TOT) return;
  int src, dst;
  if (e < E0_EDGES) { src = ei[e]; dst = ei[E0_EDGES + e]; }
  else              { src = e - E0_EDGES; dst = src; }
  int pos = atomicAdd(&cnt[dst], 1);
  if (pos < CAP) slots[dst * CAP + pos] = src;
}

// ======================= fp32 -> bf16 conversion =============================

__global__ void convert_x_kernel(const float* __restrict__ x, ushort* __restrict__ xb) {
  size_t i = ((size_t)blockIdx.x * blockDim.x + threadIdx.x) * 4;
  if (i >= (size_t)NPAD * 512) return;
  if (i < (size_t)N_NODES * 512) {
    float4 v = *(const float4*)(x + i);
    ushort4 o;
    o.x = f2bf(v.x); o.y = f2bf(v.y); o.z = f2bf(v.z); o.w = f2bf(v.w);
    *(ushort4*)(xb + i) = o;
  } else {
    *(ushort4*)(xb + i) = make_ushort4(0, 0, 0, 0);
  }
}

// Bt[m][k] = bf16(W[k][m]); all six weight matrices in one launch (z selects)
__global__ void transpose_all_kernel(
    const float* __restrict__ W1, const float* __restrict__ lW1,
    const float* __restrict__ W2, const float* __restrict__ lW2,
    const float* __restrict__ W3, const float* __restrict__ lW3,
    ushort* __restrict__ Bt1, ushort* __restrict__ Bt2, ushort* __restrict__ Bt3) {
  __shared__ float tile[32][33];
  const int K = 512;
  int z = blockIdx.z;
  const float* W; ushort* B; int M;
  switch (z) {
    case 0:  W = W1;  B = Bt1;              M = 512; break;
    case 1:  W = lW1; B = Bt1 + 512 * 512;  M = 512; break;
    case 2:  W = W2;  B = Bt2;              M = 512; break;
    case 3:  W = lW2; B = Bt2 + 512 * 512;  M = 512; break;
    case 4:  W = W3;  B = Bt3;              M = 384; break;
    default: W = lW3; B = Bt3 + 384 * 512;  M = 64;  break;
  }
  int mb = blockIdx.x * 32, kb = blockIdx.y * 32;
  if (mb >= M) return;
  int tx = threadIdx.x, ty = threadIdx.y;  // 32 x 8
#pragma unroll
  for (int i = 0; i < 32; i += 8)
    tile[ty + i][tx] = W[(size_t)(kb + ty + i) * M + mb + tx];
  __syncthreads();
#pragma unroll
  for (int i = 0; i < 32; i += 8)
    B[(size_t)(mb + ty + i) * K + kb + tx] = f2bf(tile[tx][ty + i]);
}

// ==== bf16 MFMA GEMM: persistent, 128x128, BK=32; A via 3-slot LDS ring, ====
// ==== B direct global->VGPR per step (L2-resident panel). =================
// Per iter: [vmcnt(2)+lgkm(0)] [barrier] [load B(k)->regs] [stage A(k+2)]
// [4x ds_read af + 16 MFMA]. LDS reads halved -> 64 FLOP/LDS-byte.

template <typename Out1T>
__global__ __launch_bounds__(256, 4) void mfma_gemm_kernel(
    const ushort* __restrict__ A,   // [NPAD][512] bf16
    const ushort* __restrict__ Bt,  // [colpad][512] bf16
    ushort* __restrict__ out0, int ld0, int split,
    Out1T* __restrict__ out1, int ld1, int Mout1, const float* __restrict__ bias1,
    const float* __restrict__ att_sw, const float* __restrict__ att_dw,  // [H][C]
    float* __restrict__ a_sp, float* __restrict__ a_dp,  // [N*H*2] half-parts
    int nheads, int headC,
    int NT, int nwg) {
  const int K = 512;
  __shared__ __attribute__((aligned(16))) ushort As[3][128][32];

  int tid = threadIdx.x, lane = tid & 63, wave = tid >> 6;
  int wrow = (wave >> 1) * 64, wcol = (wave & 1) * 64;

  size_t K2 = (size_t)K * 2;
  // A staging: wave covers tile rows [wave*32, +32), 2 loads x 16 rows.
  // lane -> row lane>>2, LDS chunk lane&3; SOURCE chunk = (lane&3) ^ SW(row)
  int rofs = lane >> 2;
  int gch = (lane & 3) ^ SW(rofs);
  int srow[2];
#pragma unroll
  for (int it = 0; it < 2; ++it) srow[it] = wave * 32 + it * 16;

  int fr = lane & 15, hi = lane >> 4;
  int rch = hi ^ SW(fr);  // A read-side swizzled chunk

  char* AsB = (char*)&As[0][0][0];

  int q = nwg >> 3, r = nwg & 7;

  for (int w0 = blockIdx.x; w0 < nwg; w0 += gridDim.x) {
    // bijective XCD-chunked swizzle (m204); row-panel-major linearization
    int xcd = w0 & 7, pos = w0 >> 3;
    int wgid = (xcd < r ? xcd * (q + 1) : r * (q + 1) + (xcd - r) * q) + pos;
    int by = wgid / NT, bx = wgid - by * NT;
    int bm = by * 128, bn = bx * 128;

    const char* pA[2];
#pragma unroll
    for (int it = 0; it < 2; ++it)
      pA[it] = (const char*)A + (size_t)(bm + srow[it] + rofs) * K2 + gch * 16;
    // B fragment base pointers: lane's 4 rows, 16B at col-chunk hi
    const char* pBf[4];
#pragma unroll
    for (int j = 0; j < 4; ++j)
      pBf[j] = (const char*)Bt + (size_t)(bn + wcol + j * 16 + fr) * K2 + hi * 16;

    f32x4 acc[4][4] = {};

    // prologue: stage A for steps 0,1 (slots 0,1) -> 4 outstanding/wave
#pragma unroll
    for (int s = 0; s < 2; ++s) {
#pragma unroll
      for (int it = 0; it < 2; ++it)
        GLOAD16(pA[it], AsB + s * 8192 + srow[it] * 64);
#pragma unroll
      for (int it = 0; it < 2; ++it) pA[it] += 64;
    }

    // 16 K-steps; A slot k%3, stage A(k+2) after barrier; B(k) global->reg.
#pragma unroll
    for (int k = 0; k < 16; ++k) {
      // A(k) landed (in-order: only A(k+1)'s 2 may remain); my LDS reads of
      // step k-1 executed (slot-reuse safety).
      if (k < 15) asm volatile("s_waitcnt vmcnt(2) lgkmcnt(0)" ::: "memory");
      else        asm volatile("s_waitcnt vmcnt(0) lgkmcnt(0)" ::: "memory");
      __builtin_amdgcn_s_barrier();   // step-k A ready everywhere; k-1 consumed
      asm volatile("" ::: "memory");
      // B fragments for this step, straight from L2 (no LDS)
      bf16x8 bf[4];
#pragma unroll
      for (int j = 0; j < 4; ++j)
        bf[j] = *(const bf16x8*)(pBf[j] + k * 64);
      asm volatile("" ::: "memory");  // keep A-stage AFTER B loads (FIFO count)
      if (k + 2 < 16) {               // stage A(k+2) (overwrites slot of k-1)
        int ss = (k + 2) % 3;
#pragma unroll
        for (int it = 0; it < 2; ++it)
          GLOAD16(pA[it], AsB + ss * 8192 + srow[it] * 64);
#pragma unroll
        for (int it = 0; it < 2; ++it) pA[it] += 64;
      }
      {
        int sc = k % 3;
        bf16x8 af[4];
#pragma unroll
        for (int i = 0; i < 4; ++i)
          af[i] = *(const bf16x8*)&As[sc][wrow + i * 16 + fr][rch * 8];
#pragma unroll
        for (int i = 0; i < 4; ++i)
#pragma unroll
          for (int j = 0; j < 4; ++j)
            acc[i][j] = __builtin_amdgcn_mfma_f32_16x16x32_bf16(af[i], bf[j], acc[i][j], 0, 0, 0);
      }
      asm volatile("" ::: "memory");
    }

    // tile seam: all waves' step-15 LDS reads done before next prologue stages
    asm volatile("s_waitcnt lgkmcnt(0)" ::: "memory");
    __builtin_amdgcn_s_barrier();
    asm volatile("" ::: "memory");

    // ---- epilogue: C/D layout col=lane&15, row=(lane>>4)*4+reg [m89/m91] ----
    int colg = bn + wcol;            // 64-aligned, wave-uniform
    bool lower = colg < split;
    int g4 = hi << 2;
    int ccol = fr;
#pragma unroll
    for (int i = 0; i < 4; ++i) {
#pragma unroll
      for (int rr = 0; rr < 4; ++rr) {
        int row = bm + wrow + g4 + i * 16 + rr;
        if (row >= N_NODES) continue;
#pragma unroll
        for (int j = 0; j < 4; ++j) {
          int col = colg + j * 16 + ccol;
          float v = acc[i][j][rr];
          if (lower) {
            out0[(size_t)row * ld0 + col] = f2bf(v);
          } else {
            int c1 = col - split;
            if (c1 < Mout1) {
              float b = v + bias1[c1];
              if constexpr (std::is_same<Out1T, ushort>::value)
                out1[(size_t)row * ld1 + c1] = f2bf(b);
              else
                out1[(size_t)row * ld1 + c1] = b;
            }
          }
        }
      }
    }

    // ---- fused attention scores: a_s/a_d = h . att over this wave's 64 cols --
    if (lower) {
      int hd = colg / headC;               // wave-uniform head
      int cb = colg - hd * headC;          // 0 or 64
      int half = (cb >> 6) & 1;
      float ws4[4], wd4[4];
#pragma unroll
      for (int j = 0; j < 4; ++j) {
        int cc = hd * headC + cb + j * 16 + ccol;
        ws4[j] = att_sw[cc];
        wd4[j] = att_dw[cc];
      }
#pragma unroll
      for (int i = 0; i < 4; ++i) {
#pragma unroll
        for (int rr = 0; rr < 4; ++rr) {
          float ps = 0.f, pd = 0.f;
#pragma unroll
          for (int j = 0; j < 4; ++j) { ps += acc[i][j][rr] * ws4[j]; pd += acc[i][j][rr] * wd4[j]; }
#pragma unroll
          for (int o = 1; o < 16; o <<= 1) { ps += __shfl_xor(ps, o); pd += __shfl_xor(pd, o); }
          if ((lane & 15) == 0) {
            int row = bm + wrow + g4 + i * 16 + rr;
            if (row < N_NODES) {
              size_t idx = ((size_t)row * nheads + hd) * 2;
              if (headC == 128) {
                a_sp[idx + half] = ps;
                a_dp[idx + half] = pd;
              } else {
                a_sp[idx] = ps;  a_sp[idx + 1] = 0.f;
                a_dp[idx] = pd;  a_dp[idx + 1] = 0.f;
              }
            }
          }
        }
      }
    }
  }
}

// ======================= fused softmax + gather (layers 1,2) =================
// 128 threads: 2 waves do softmax for 2 heads each; then thread t owns
// features 4t..4t+3 (head = t>>5), 8B vector loads per edge.

template <int H, int C>
__global__ __launch_bounds__(128) void gather12_fused(
    const int* __restrict__ cnt, const int* __restrict__ slots,
    const float* __restrict__ a_sp, const float* __restrict__ a_dp,
    const ushort* __restrict__ hbuf, const float* __restrict__ gat_bias,
    const ushort* __restrict__ skip_in, ushort* __restrict__ outbuf) {
  __shared__ float al[H][CAP];
  __shared__ int srcs[CAP];
  int n = blockIdx.x;
  int t = threadIdx.x, lane = t & 63, w = t >> 6;  // 2 waves
  int deg = min(cnt[n], CAP);

  int sj = 0;
  if (lane < deg) sj = slots[n * CAP + lane];
#pragma unroll
  for (int hh = 0; hh < 2; ++hh) {
    int hd = 2 * w + hh;
    float e = -1e30f;
    if (lane < deg) {
      size_t is = ((size_t)sj * H + hd) * 2;
      size_t id = ((size_t)n * H + hd) * 2;
      float v = a_sp[is] + a_sp[is + 1] + a_dp[id] + a_dp[id + 1];
      e = v > 0.f ? v : 0.2f * v;  // leaky_relu
    }
    float m = e;
#pragma unroll
    for (int o = 32; o > 0; o >>= 1) m = fmaxf(m, __shfl_xor(m, o));
    float ex = (lane < deg) ? expf(e - m) : 0.f;
    float s = ex;
#pragma unroll
    for (int o = 32; o > 0; o >>= 1) s += __shfl_xor(s, o);
    float inv = 1.f / (s + 1e-16f);
    if (lane < deg) al[hd][lane] = ex * inv;
  }
  if (w == 0 && lane < deg) srcs[lane] = sj;
  __syncthreads();

  int f0 = 4 * t, hd = t >> 5;  // features 4t..4t+3, all in head t>>5
  float a0 = 0.f, a1 = 0.f, a2 = 0.f, a3 = 0.f;
  for (int j = 0; j < deg; ++j) {
    float a = al[hd][j];
    ushort4 hv = *(const ushort4*)(hbuf + (size_t)srcs[j] * (H * C) + f0);
    a0 += a * bf2f(hv.x);
    a1 += a * bf2f(hv.y);
    a2 += a * bf2f(hv.z);
    a3 += a * bf2f(hv.w);
  }
  ushort4 sk = *(const ushort4*)(skip_in + (size_t)n * (H * C) + f0);
  float o0 = a0 + gat_bias[f0 + 0] + bf2f(sk.x);
  float o1 = a1 + gat_bias[f0 + 1] + bf2f(sk.y);
  float o2 = a2 + gat_bias[f0 + 2] + bf2f(sk.z);
  float o3 = a3 + gat_bias[f0 + 3] + bf2f(sk.w);
  o0 = o0 > 0.f ? o0 : (expf(o0) - 1.f);  // ELU
  o1 = o1 > 0.f ? o1 : (expf(o1) - 1.f);
  o2 = o2 > 0.f ? o2 : (expf(o2) - 1.f);
  o3 = o3 > 0.f ? o3 : (expf(o3) - 1.f);
  ushort4 ov;
  ov.x = f2bf(o0); ov.y = f2bf(o1); ov.z = f2bf(o2); ov.w = f2bf(o3);
  *(ushort4*)(outbuf + (size_t)n * (H * C) + f0) = ov;
}

// ======================= fused softmax + gather (layer 3, mean heads) ========

__global__ __launch_bounds__(128) void gather3_fused(
    const int* __restrict__ cnt, const int* __restrict__ slots,
    const float* __restrict__ a_sp, const float* __restrict__ a_dp,
    const ushort* __restrict__ hbuf /*N x 384*/, const float* __restrict__ b3,
    float* __restrict__ out /*N x 64, holds skip+lb3*/) {
  __shared__ float al[6][CAP];
  __shared__ int srcs[CAP];
  __shared__ float part[2][64];
  int n = blockIdx.x;
  int t = threadIdx.x, lane = t & 63, w = t >> 6;
  int deg = min(cnt[n], CAP);

  int sj = 0;
  if (lane < deg) sj = slots[n * CAP + lane];
#pragma unroll
  for (int hh = 0; hh < 3; ++hh) {
    int hd = 3 * w + hh;
    float e = -1e30f;
    if (lane < deg) {
      size_t is = ((size_t)sj * 6 + hd) * 2;
      size_t id = ((size_t)n * 6 + hd) * 2;
      float v = a_sp[is] + a_sp[is + 1] + a_dp[id] + a_dp[id + 1];
      e = v > 0.f ? v : 0.2f * v;
    }
    float m = e;
#pragma unroll
    for (int o = 32; o > 0; o >>= 1) m = fmaxf(m, __shfl_xor(m, o));
    float ex = (lane < deg) ? expf(e - m) : 0.f;
    float s = ex;
#pragma unroll
    for (int o = 32; o > 0; o >>= 1) s += __shfl_xor(s, o);
    float inv = (1.f / 6.f) / (s + 1e-16f);  // fold mean over heads
    if (lane < deg) al[hd][lane] = ex * inv;
  }
  if (w == 0 && lane < deg) srcs[lane] = sj;
  __syncthreads();

  int c = t & 63;
  float acc = 0.f;
  for (int j = w; j < deg; j += 2) {
    const ushort* hr = hbuf + (size_t)srcs[j] * 384 + c;
#pragma unroll
    for (int hd = 0; hd < 6; ++hd) acc += al[hd][j] * bf2f(hr[hd * 64]);
  }
  part[w][c] = acc;
  __syncthreads();
  if (t < 64) {
    size_t oi = (size_t)n * 64 + t;
    out[oi] += part[0][t] + part[1][t] + b3[t];
  }
}

// ======================= host launch =========================================

extern "C" void kernel_launch(void* const* d_in, const int* in_sizes, int n_in,
                              void* d_out, int out_size, void* d_ws, size_t ws_size,
                              hipStream_t stream) {
  const float* x   = (const float*)d_in[0];
  const int*   ei  = (const int*)d_in[1];
  const float* W1  = (const float*)d_in[2];
  const float* as1 = (const float*)d_in[3];
  const float* ad1 = (const float*)d_in[4];
  const float* b1  = (const float*)d_in[5];
  const float* lW1 = (const float*)d_in[6];
  const float* lb1 = (const float*)d_in[7];
  const float* W2  = (const float*)d_in[8];
  const float* as2 = (const float*)d_in[9];
  const float* ad2 = (const float*)d_in[10];
  const float* b2  = (const float*)d_in[11];
  const float* lW2 = (const float*)d_in[12];
  const float* lb2 = (const float*)d_in[13];
  const float* W3  = (const float*)d_in[14];
  const float* as3 = (const float*)d_in[15];
  const float* ad3 = (const float*)d_in[16];
  const float* b3  = (const float*)d_in[17];
  const float* lW3 = (const float*)d_in[18];
  const float* lb3 = (const float*)d_in[19];
  float* out = (float*)d_out;

  char* ws = (char*)d_ws;
  auto alloc = [&](size_t bytes) -> void* {
    void* p = (void*)ws;
    ws += (bytes + 255) & ~(size_t)255;
    return p;
  };
  ushort* xb    = (ushort*)alloc((size_t)NPAD * 512 * 2);
  ushort* Pb    = (ushort*)alloc((size_t)NPAD * 512 * 2);
  ushort* Qb    = (ushort*)alloc((size_t)NPAD * 512 * 2);
  ushort* skipb = (ushort*)alloc((size_t)N_NODES * 512 * 2);
  ushort* hb    = (ushort*)alloc((size_t)N_NODES * 512 * 2);
  ushort* Bt1   = (ushort*)alloc((size_t)1024 * 512 * 2);
  ushort* Bt2   = (ushort*)alloc((size_t)1024 * 512 * 2);
  ushort* Bt3   = (ushort*)alloc((size_t)512 * 512 * 2);
  float*  a_sp  = (float*)alloc((size_t)N_NODES * 6 * 2 * 4);
  float*  a_dp  = (float*)alloc((size_t)N_NODES * 6 * 2 * 4);
  int*    cnt   = (int*)alloc((size_t)N_NODES * 4);
  int*    slots = (int*)alloc((size_t)N_NODES * CAP * 4);

  // ---- CSR slots ----
  hipMemsetAsync(cnt, 0, N_NODES * sizeof(int), stream);
  fill_csr_kernel<<<(E_TOT + 255) / 256, 256, 0, stream>>>(ei, cnt, slots);

  // ---- conversions / weight transposes ----
  convert_x_kernel<<<((NPAD * 512 / 4) + 255) / 256, 256, 0, stream>>>(x, xb);
  transpose_all_kernel<<<dim3(16, 16, 6), dim3(32, 8), 0, stream>>>(
      W1, lW1, W2, lW2, W3, lW3, Bt1, Bt2, Bt3);

  const int NBY = NPAD / 128;          // 157 row tiles
  const int NWG12 = NBY * 8;           // 1256 tiles (8 col tiles of 128)
  const int NWG3  = NBY * 4;           // 628 tiles  (4 col tiles of 128)
  const int PERSIST = 256 * 4;         // 4 blocks/CU co-resident
  const int G12 = NWG12 < PERSIST ? NWG12 : PERSIST;  // 1024
  const int G3  = NWG3  < PERSIST ? NWG3  : PERSIST;  // 628

  // ---- layer 1 ----
  mfma_gemm_kernel<ushort><<<G12, 256, 0, stream>>>(
      xb, Bt1, hb, 512, 512, skipb, 512, 512, lb1, as1, ad1, a_sp, a_dp, 4, 128,
      8, NWG12);
  gather12_fused<4, 128><<<N_NODES, 128, 0, stream>>>(cnt, slots, a_sp, a_dp, hb, b1, skipb, Pb);

  // ---- layer 2 ----
  mfma_gemm_kernel<ushort><<<G12, 256, 0, stream>>>(
      Pb, Bt2, hb, 512, 512, skipb, 512, 512, lb2, as2, ad2, a_sp, a_dp, 4, 128,
      8, NWG12);
  gather12_fused<4, 128><<<N_NODES, 128, 0, stream>>>(cnt, slots, a_sp, a_dp, hb, b2, skipb, Qb);

  // ---- layer 3 ----
  mfma_gemm_kernel<float><<<G3, 256, 0, stream>>>(
      Qb, Bt3, hb, 384, 384, out, 64, 64, lb3, as3, ad3, a_sp, a_dp, 6, 64,
      4, NWG3);
  gather3_fused<<<N_NODES, 128, 0, stream>>>(cnt, slots, a_sp, a_dp, hb, b3, out);
}

// Round 13
// 312.963 us; speedup vs baseline: 1.0384x; 1.0384x over previous
//
#include <hip/hip_runtime.h>
#include <cstddef>
#include <cstdint>
#include <type_traits>

#define N_NODES 20000
#define NPAD 20096            // multiple of 128 for MFMA row tiles
#define E0_EDGES 160000
#define E_TOT (E0_EDGES + N_NODES)
#define CAP 64                // max in-degree slots (Poisson(9); P(>=64) ~ 0)

typedef __bf16 bf16x8 __attribute__((ext_vector_type(8)));
typedef float f32x4 __attribute__((ext_vector_type(4)));

__device__ __forceinline__ ushort f2bf(float f) {
  uint32_t u = __float_as_uint(f);
  return (ushort)((u + 0x7FFFu + ((u >> 16) & 1u)) >> 16);  // RNE
}
__device__ __forceinline__ float bf2f(ushort h) {
  return __uint_as_float((uint32_t)h << 16);
}

// chunk swizzle for 64B LDS rows
__device__ __forceinline__ int SW(int r) { return ((r >> 1) & 3) ^ ((r >> 3) & 1); }

// async global->LDS, 16B/lane; LDS dest = wave-uniform base + lane*16
#define GLOAD16(g, l)                                                         \
  __builtin_amdgcn_global_load_lds(                                           \
      (const __attribute__((address_space(1))) void*)(uintptr_t)(g),          \
      (__attribute__((address_space(3))) void*)(uint32_t)(uintptr_t)(l),      \
      16, 0, 0)

// ======================= CSR via fixed-stride slots ==========================

__global__ void fill_csr_kernel(const int* __restrict__ ei, int* __restrict__ cnt,
                                int* __restrict__ slots) {
  int e = blockIdx.x * blockDim.x + threadIdx.x;
  if (e >= E_TOT) return;
  int src, dst;
  if (e < E0_EDGES) { src = ei[e]; dst = ei[E0_EDGES + e]; }
  else              { src = e - E0_EDGES; dst = src; }
  int pos = atomicAdd(&cnt[dst], 1);
  if (pos < CAP) slots[dst * CAP + pos] = src;
}

// ======================= fp32 -> bf16 conversion =============================

__global__ void convert_x_kernel(const float* __restrict__ x, ushort* __restrict__ xb) {
  size_t i = ((size_t)blockIdx.x * blockDim.x + threadIdx.x) * 4;
  if (i >= (size_t)NPAD * 512) return;
  if (i < (size_t)N_NODES * 512) {
    float4 v = *(const float4*)(x + i);
    ushort4 o;
    o.x = f2bf(v.x); o.y = f2bf(v.y); o.z = f2bf(v.z); o.w = f2bf(v.w);
    *(ushort4*)(xb + i) = o;
  } else {
    *(ushort4*)(xb + i) = make_ushort4(0, 0, 0, 0);
  }
}

// Bt[m][k] = bf16(W[k][m]); all six weight matrices in one launch (z selects)
__global__ void transpose_all_kernel(
    const float* __restrict__ W1, const float* __restrict__ lW1,
    const float* __restrict__ W2, const float* __restrict__ lW2,
    const float* __restrict__ W3, const float* __restrict__ lW3,
    ushort* __restrict__ Bt1, ushort* __restrict__ Bt2, ushort* __restrict__ Bt3) {
  __shared__ float tile[32][33];
  const int K = 512;
  int z = blockIdx.z;
  const float* W; ushort* B; int M;
  switch (z) {
    case 0:  W = W1;  B = Bt1;              M = 512; break;
    case 1:  W = lW1; B = Bt1 + 512 * 512;  M = 512; break;
    case 2:  W = W2;  B = Bt2;              M = 512; break;
    case 3:  W = lW2; B = Bt2 + 512 * 512;  M = 512; break;
    case 4:  W = W3;  B = Bt3;              M = 384; break;
    default: W = lW3; B = Bt3 + 384 * 512;  M = 64;  break;
  }
  int mb = blockIdx.x * 32, kb = blockIdx.y * 32;
  if (mb >= M) return;
  int tx = threadIdx.x, ty = threadIdx.y;  // 32 x 8
#pragma unroll
  for (int i = 0; i < 32; i += 8)
    tile[ty + i][tx] = W[(size_t)(kb + ty + i) * M + mb + tx];
  __syncthreads();
#pragma unroll
  for (int i = 0; i < 32; i += 8)
    B[(size_t)(mb + ty + i) * K + kb + tx] = f2bf(tile[tx][ty + i]);
}

// ==== bf16 MFMA GEMM: persistent, 128x128, BK=32; A via 3-slot LDS ring, ====
// ==== B direct global->VGPR per step (L2-resident panel). ===================
// launch_bounds(256,3): VGPR cap ~170 so acc NEVER spills (r12 lesson).
// Dynamic K-loop + pointer increments keep address working set small.

template <typename Out1T>
__global__ __launch_bounds__(256, 3) void mfma_gemm_kernel(
    const ushort* __restrict__ A,   // [NPAD][512] bf16
    const ushort* __restrict__ Bt,  // [colpad][512] bf16
    ushort* __restrict__ out0, int ld0, int split,
    Out1T* __restrict__ out1, int ld1, int Mout1, const float* __restrict__ bias1,
    const float* __restrict__ att_sw, const float* __restrict__ att_dw,  // [H][C]
    float* __restrict__ a_sp, float* __restrict__ a_dp,  // [N*H*2] half-parts
    int nheads, int headC,
    int NT, int nwg) {
  const int K = 512;
  __shared__ __attribute__((aligned(16))) ushort As[3][128][32];

  int tid = threadIdx.x, lane = tid & 63, wave = tid >> 6;
  int wrow = (wave >> 1) * 64, wcol = (wave & 1) * 64;

  size_t K2 = (size_t)K * 2;
  // A staging: wave covers tile rows [wave*32, +32), 2 loads x 16 rows.
  // lane -> row lane>>2, LDS chunk lane&3; SOURCE chunk = (lane&3) ^ SW(row)
  int rofs = lane >> 2;
  int gch = (lane & 3) ^ SW(rofs);
  int srow[2];
#pragma unroll
  for (int it = 0; it < 2; ++it) srow[it] = wave * 32 + it * 16;

  int fr = lane & 15, hi = lane >> 4;
  int rch = hi ^ SW(fr);  // A read-side swizzled chunk

  char* AsB = (char*)&As[0][0][0];

  int q = nwg >> 3, r = nwg & 7;

  for (int w0 = blockIdx.x; w0 < nwg; w0 += gridDim.x) {
    // bijective XCD-chunked swizzle (m204); row-panel-major linearization
    int xcd = w0 & 7, pos = w0 >> 3;
    int wgid = (xcd < r ? xcd * (q + 1) : r * (q + 1) + (xcd - r) * q) + pos;
    int by = wgid / NT, bx = wgid - by * NT;
    int bm = by * 128, bn = bx * 128;

    const char* pA[2];
#pragma unroll
    for (int it = 0; it < 2; ++it)
      pA[it] = (const char*)A + (size_t)(bm + srow[it] + rofs) * K2 + gch * 16;
    // B fragment base pointers: lane's 4 rows, 16B at col-chunk hi
    const char* pBf[4];
#pragma unroll
    for (int j = 0; j < 4; ++j)
      pBf[j] = (const char*)Bt + (size_t)(bn + wcol + j * 16 + fr) * K2 + hi * 16;

    f32x4 acc[4][4] = {};

    // prologue: stage A for steps 0,1 (slots 0,1) -> 4 outstanding/wave
#pragma unroll
    for (int s = 0; s < 2; ++s) {
#pragma unroll
      for (int it = 0; it < 2; ++it)
        GLOAD16(pA[it], AsB + s * 8192 + srow[it] * 64);
#pragma unroll
      for (int it = 0; it < 2; ++it) pA[it] += 64;
    }

    // 16 K-steps (dynamic loop); A slot k%3, stage A(k+2) after barrier;
    // B(k) global->reg.
    int sc = 0, ss = 2;
    for (int k = 0; k < 16; ++k) {
      // A(k) landed (in-order; only A(k+1)'s 2 may remain outstanding);
      // my LDS reads of step k-1 executed (slot-reuse safety).
      if (k < 15) asm volatile("s_waitcnt vmcnt(2) lgkmcnt(0)" ::: "memory");
      else        asm volatile("s_waitcnt vmcnt(0) lgkmcnt(0)" ::: "memory");
      __builtin_amdgcn_s_barrier();   // step-k A ready everywhere; k-1 consumed
      asm volatile("" ::: "memory");
      // B fragments for this step, straight from L2 (no LDS)
      bf16x8 bf[4];
#pragma unroll
      for (int j = 0; j < 4; ++j) bf[j] = *(const bf16x8*)pBf[j];
#pragma unroll
      for (int j = 0; j < 4; ++j) pBf[j] += 64;
      asm volatile("" ::: "memory");  // keep A-stage AFTER B loads (FIFO count)
      if (k + 2 < 16) {               // stage A(k+2) (overwrites slot of k-1)
#pragma unroll
        for (int it = 0; it < 2; ++it)
          GLOAD16(pA[it], AsB + ss * 8192 + srow[it] * 64);
#pragma unroll
        for (int it = 0; it < 2; ++it) pA[it] += 64;
      }
      {
        bf16x8 af[4];
#pragma unroll
        for (int i = 0; i < 4; ++i)
          af[i] = *(const bf16x8*)&As[sc][wrow + i * 16 + fr][rch * 8];
#pragma unroll
        for (int i = 0; i < 4; ++i)
#pragma unroll
          for (int j = 0; j < 4; ++j)
            acc[i][j] = __builtin_amdgcn_mfma_f32_16x16x32_bf16(af[i], bf[j], acc[i][j], 0, 0, 0);
      }
      asm volatile("" ::: "memory");
      sc = (sc == 2) ? 0 : sc + 1;
      ss = (ss == 2) ? 0 : ss + 1;
    }

    // tile seam: all waves' step-15 LDS reads done before next prologue stages
    asm volatile("s_waitcnt lgkmcnt(0)" ::: "memory");
    __builtin_amdgcn_s_barrier();
    asm volatile("" ::: "memory");

    // ---- epilogue: C/D layout col=lane&15, row=(lane>>4)*4+reg [m89/m91] ----
    int colg = bn + wcol;            // 64-aligned, wave-uniform
    bool lower = colg < split;
    int g4 = hi << 2;
    int ccol = fr;
#pragma unroll
    for (int i = 0; i < 4; ++i) {
#pragma unroll
      for (int rr = 0; rr < 4; ++rr) {
        int row = bm + wrow + g4 + i * 16 + rr;
        if (row >= N_NODES) continue;
#pragma unroll
        for (int j = 0; j < 4; ++j) {
          int col = colg + j * 16 + ccol;
          float v = acc[i][j][rr];
          if (lower) {
            out0[(size_t)row * ld0 + col] = f2bf(v);
          } else {
            int c1 = col - split;
            if (c1 < Mout1) {
              float b = v + bias1[c1];
              if constexpr (std::is_same<Out1T, ushort>::value)
                out1[(size_t)row * ld1 + c1] = f2bf(b);
              else
                out1[(size_t)row * ld1 + c1] = b;
            }
          }
        }
      }
    }

    // ---- fused attention scores: a_s/a_d = h . att over this wave's 64 cols --
    if (lower) {
      int hd = colg / headC;               // wave-uniform head
      int cb = colg - hd * headC;          // 0 or 64
      int half = (cb >> 6) & 1;
      float ws4[4], wd4[4];
#pragma unroll
      for (int j = 0; j < 4; ++j) {
        int cc = hd * headC + cb + j * 16 + ccol;
        ws4[j] = att_sw[cc];
        wd4[j] = att_dw[cc];
      }
#pragma unroll
      for (int i = 0; i < 4; ++i) {
#pragma unroll
        for (int rr = 0; rr < 4; ++rr) {
          float ps = 0.f, pd = 0.f;
#pragma unroll
          for (int j = 0; j < 4; ++j) { ps += acc[i][j][rr] * ws4[j]; pd += acc[i][j][rr] * wd4[j]; }
#pragma unroll
          for (int o = 1; o < 16; o <<= 1) { ps += __shfl_xor(ps, o); pd += __shfl_xor(pd, o); }
          if ((lane & 15) == 0) {
            int row = bm + wrow + g4 + i * 16 + rr;
            if (row < N_NODES) {
              size_t idx = ((size_t)row * nheads + hd) * 2;
              if (headC == 128) {
                a_sp[idx + half] = ps;
                a_dp[idx + half] = pd;
              } else {
                a_sp[idx] = ps;  a_sp[idx + 1] = 0.f;
                a_dp[idx] = pd;  a_dp[idx + 1] = 0.f;
              }
            }
          }
        }
      }
    }
  }
}

// ======================= fused softmax + gather (layers 1,2) =================
// 128 threads: 2 waves do softmax for 2 heads each; then thread t owns
// features 4t..4t+3 (head = t>>5), 8B vector loads per edge.

template <int H, int C>
__global__ __launch_bounds__(128) void gather12_fused(
    const int* __restrict__ cnt, const int* __restrict__ slots,
    const float* __restrict__ a_sp, const float* __restrict__ a_dp,
    const ushort* __restrict__ hbuf, const float* __restrict__ gat_bias,
    const ushort* __restrict__ skip_in, ushort* __restrict__ outbuf) {
  __shared__ float al[H][CAP];
  __shared__ int srcs[CAP];
  int n = blockIdx.x;
  int t = threadIdx.x, lane = t & 63, w = t >> 6;  // 2 waves
  int deg = min(cnt[n], CAP);

  int sj = 0;
  if (lane < deg) sj = slots[n * CAP + lane];
#pragma unroll
  for (int hh = 0; hh < 2; ++hh) {
    int hd = 2 * w + hh;
    float e = -1e30f;
    if (lane < deg) {
      size_t is = ((size_t)sj * H + hd) * 2;
      size_t id = ((size_t)n * H + hd) * 2;
      float v = a_sp[is] + a_sp[is + 1] + a_dp[id] + a_dp[id + 1];
      e = v > 0.f ? v : 0.2f * v;  // leaky_relu
    }
    float m = e;
#pragma unroll
    for (int o = 32; o > 0; o >>= 1) m = fmaxf(m, __shfl_xor(m, o));
    float ex = (lane < deg) ? expf(e - m) : 0.f;
    float s = ex;
#pragma unroll
    for (int o = 32; o > 0; o >>= 1) s += __shfl_xor(s, o);
    float inv = 1.f / (s + 1e-16f);
    if (lane < deg) al[hd][lane] = ex * inv;
  }
  if (w == 0 && lane < deg) srcs[lane] = sj;
  __syncthreads();

  int f0 = 4 * t, hd = t >> 5;  // features 4t..4t+3, all in head t>>5
  float a0 = 0.f, a1 = 0.f, a2 = 0.f, a3 = 0.f;
  for (int j = 0; j < deg; ++j) {
    float a = al[hd][j];
    ushort4 hv = *(const ushort4*)(hbuf + (size_t)srcs[j] * (H * C) + f0);
    a0 += a * bf2f(hv.x);
    a1 += a * bf2f(hv.y);
    a2 += a * bf2f(hv.z);
    a3 += a * bf2f(hv.w);
  }
  ushort4 sk = *(const ushort4*)(skip_in + (size_t)n * (H * C) + f0);
  float o0 = a0 + gat_bias[f0 + 0] + bf2f(sk.x);
  float o1 = a1 + gat_bias[f0 + 1] + bf2f(sk.y);
  float o2 = a2 + gat_bias[f0 + 2] + bf2f(sk.z);
  float o3 = a3 + gat_bias[f0 + 3] + bf2f(sk.w);
  o0 = o0 > 0.f ? o0 : (expf(o0) - 1.f);  // ELU
  o1 = o1 > 0.f ? o1 : (expf(o1) - 1.f);
  o2 = o2 > 0.f ? o2 : (expf(o2) - 1.f);
  o3 = o3 > 0.f ? o3 : (expf(o3) - 1.f);
  ushort4 ov;
  ov.x = f2bf(o0); ov.y = f2bf(o1); ov.z = f2bf(o2); ov.w = f2bf(o3);
  *(ushort4*)(outbuf + (size_t)n * (H * C) + f0) = ov;
}

// ======================= fused softmax + gather (layer 3, mean heads) ========

__global__ __launch_bounds__(128) void gather3_fused(
    const int* __restrict__ cnt, const int* __restrict__ slots,
    const float* __restrict__ a_sp, const float* __restrict__ a_dp,
    const ushort* __restrict__ hbuf /*N x 384*/, const float* __restrict__ b3,
    float* __restrict__ out /*N x 64, holds skip+lb3*/) {
  __shared__ float al[6][CAP];
  __shared__ int srcs[CAP];
  __shared__ float part[2][64];
  int n = blockIdx.x;
  int t = threadIdx.x, lane = t & 63, w = t >> 6;
  int deg = min(cnt[n], CAP);

  int sj = 0;
  if (lane < deg) sj = slots[n * CAP + lane];
#pragma unroll
  for (int hh = 0; hh < 3; ++hh) {
    int hd = 3 * w + hh;
    float e = -1e30f;
    if (lane < deg) {
      size_t is = ((size_t)sj * 6 + hd) * 2;
      size_t id = ((size_t)n * 6 + hd) * 2;
      float v = a_sp[is] + a_sp[is + 1] + a_dp[id] + a_dp[id + 1];
      e = v > 0.f ? v : 0.2f * v;
    }
    float m = e;
#pragma unroll
    for (int o = 32; o > 0; o >>= 1) m = fmaxf(m, __shfl_xor(m, o));
    float ex = (lane < deg) ? expf(e - m) : 0.f;
    float s = ex;
#pragma unroll
    for (int o = 32; o > 0; o >>= 1) s += __shfl_xor(s, o);
    float inv = (1.f / 6.f) / (s + 1e-16f);  // fold mean over heads
    if (lane < deg) al[hd][lane] = ex * inv;
  }
  if (w == 0 && lane < deg) srcs[lane] = sj;
  __syncthreads();

  int c = t & 63;
  float acc = 0.f;
  for (int j = w; j < deg; j += 2) {
    const ushort* hr = hbuf + (size_t)srcs[j] * 384 + c;
#pragma unroll
    for (int hd = 0; hd < 6; ++hd) acc += al[hd][j] * bf2f(hr[hd * 64]);
  }
  part[w][c] = acc;
  __syncthreads();
  if (t < 64) {
    size_t oi = (size_t)n * 64 + t;
    out[oi] += part[0][t] + part[1][t] + b3[t];
  }
}

// ======================= host launch =========================================

extern "C" void kernel_launch(void* const* d_in, const int* in_sizes, int n_in,
                              void* d_out, int out_size, void* d_ws, size_t ws_size,
                              hipStream_t stream) {
  const float* x   = (const float*)d_in[0];
  const int*   ei  = (const int*)d_in[1];
  const float* W1  = (const float*)d_in[2];
  const float* as1 = (const float*)d_in[3];
  const float* ad1 = (const float*)d_in[4];
  const float* b1  = (const float*)d_in[5];
  const float* lW1 = (const float*)d_in[6];
  const float* lb1 = (const float*)d_in[7];
  const float* W2  = (const float*)d_in[8];
  const float* as2 = (const float*)d_in[9];
  const float* ad2 = (const float*)d_in[10];
  const float* b2  = (const float*)d_in[11];
  const float* lW2 = (const float*)d_in[12];
  const float* lb2 = (const float*)d_in[13];
  const float* W3  = (const float*)d_in[14];
  const float* as3 = (const float*)d_in[15];
  const float* ad3 = (const float*)d_in[16];
  const float* b3  = (const float*)d_in[17];
  const float* lW3 = (const float*)d_in[18];
  const float* lb3 = (const float*)d_in[19];
  float* out = (float*)d_out;

  char* ws = (char*)d_ws;
  auto alloc = [&](size_t bytes) -> void* {
    void* p = (void*)ws;
    ws += (bytes + 255) & ~(size_t)255;
    return p;
  };
  ushort* xb    = (ushort*)alloc((size_t)NPAD * 512 * 2);
  ushort* Pb    = (ushort*)alloc((size_t)NPAD * 512 * 2);
  ushort* Qb    = (ushort*)alloc((size_t)NPAD * 512 * 2);
  ushort* skipb = (ushort*)alloc((size_t)N_NODES * 512 * 2);
  ushort* hb    = (ushort*)alloc((size_t)N_NODES * 512 * 2);
  ushort* Bt1   = (ushort*)alloc((size_t)1024 * 512 * 2);
  ushort* Bt2   = (ushort*)alloc((size_t)1024 * 512 * 2);
  ushort* Bt3   = (ushort*)alloc((size_t)512 * 512 * 2);
  float*  a_sp  = (float*)alloc((size_t)N_NODES * 6 * 2 * 4);
  float*  a_dp  = (float*)alloc((size_t)N_NODES * 6 * 2 * 4);
  int*    cnt   = (int*)alloc((size_t)N_NODES * 4);
  int*    slots = (int*)alloc((size_t)N_NODES * CAP * 4);

  // ---- CSR slots ----
  hipMemsetAsync(cnt, 0, N_NODES * sizeof(int), stream);
  fill_csr_kernel<<<(E_TOT + 255) / 256, 256, 0, stream>>>(ei, cnt, slots);

  // ---- conversions / weight transposes ----
  convert_x_kernel<<<((NPAD * 512 / 4) + 255) / 256, 256, 0, stream>>>(x, xb);
  transpose_all_kernel<<<dim3(16, 16, 6), dim3(32, 8), 0, stream>>>(
      W1, lW1, W2, lW2, W3, lW3, Bt1, Bt2, Bt3);

  const int NBY = NPAD / 128;          // 157 row tiles
  const int NWG12 = NBY * 8;           // 1256 tiles (8 col tiles of 128)
  const int NWG3  = NBY * 4;           // 628 tiles  (4 col tiles of 128)
  const int PERSIST = 256 * 3;         // 3 blocks/CU co-resident
  const int G12 = NWG12 < PERSIST ? NWG12 : PERSIST;  // 768
  const int G3  = NWG3  < PERSIST ? NWG3  : PERSIST;  // 628

  // ---- layer 1 ----
  mfma_gemm_kernel<ushort><<<G12, 256, 0, stream>>>(
      xb, Bt1, hb, 512, 512, skipb, 512, 512, lb1, as1, ad1, a_sp, a_dp, 4, 128,
      8, NWG12);
  gather12_fused<4, 128><<<N_NODES, 128, 0, stream>>>(cnt, slots, a_sp, a_dp, hb, b1, skipb, Pb);

  // ---- layer 2 ----
  mfma_gemm_kernel<ushort><<<G12, 256, 0, stream>>>(
      Pb, Bt2, hb, 512, 512, skipb, 512, 512, lb2, as2, ad2, a_sp, a_dp, 4, 128,
      8, NWG12);
  gather12_fused<4, 128><<<N_NODES, 128, 0, stream>>>(cnt, slots, a_sp, a_dp, hb, b2, skipb, Qb);

  // ---- layer 3 ----
  mfma_gemm_kernel<float><<<G3, 256, 0, stream>>>(
      Qb, Bt3, hb, 384, 384, out, 64, 64, lb3, as3, ad3, a_sp, a_dp, 6, 64,
      4, NWG3);
  gather3_fused<<<N_NODES, 128, 0, stream>>>(cnt, slots, a_sp, a_dp, hb, b3, out);
}

// Round 14
// 256.436 us; speedup vs baseline: 1.2673x; 1.2204x over previous
//
#include <hip/hip_runtime.h>
#include <cstddef>
#include <cstdint>
#include <type_traits>

#define N_NODES 20000
#define NPAD 20096            // multiple of 128 for MFMA row tiles
#define E0_EDGES 160000
#define E_TOT (E0_EDGES + N_NODES)
#define CAP 64                // max in-degree slots (Poisson(9); P(>=64) ~ 0)

typedef __bf16 bf16x8 __attribute__((ext_vector_type(8)));
typedef float f32x4 __attribute__((ext_vector_type(4)));
typedef ushort ushort8 __attribute__((ext_vector_type(8)));

__device__ __forceinline__ ushort f2bf(float f) {
  uint32_t u = __float_as_uint(f);
  return (ushort)((u + 0x7FFFu + ((u >> 16) & 1u)) >> 16);  // RNE
}
__device__ __forceinline__ float bf2f(ushort h) {
  return __uint_as_float((uint32_t)h << 16);
}

// chunk swizzle for 64B LDS rows
__device__ __forceinline__ int SW(int r) { return ((r >> 1) & 3) ^ ((r >> 3) & 1); }

// async global->LDS, 16B/lane; LDS dest = wave-uniform base + lane*16
#define GLOAD16(g, l)                                                         \
  __builtin_amdgcn_global_load_lds(                                           \
      (const __attribute__((address_space(1))) void*)(uintptr_t)(g),          \
      (__attribute__((address_space(3))) void*)(uint32_t)(uintptr_t)(l),      \
      16, 0, 0)

// ======================= CSR via fixed-stride slots ==========================

__global__ void fill_csr_kernel(const int* __restrict__ ei, int* __restrict__ cnt,
                                int* __restrict__ slots) {
  int e = blockIdx.x * blockDim.x + threadIdx.x;
  if (e >= E_TOT) return;
  int src, dst;
  if (e < E0_EDGES) { src = ei[e]; dst = ei[E0_EDGES + e]; }
  else              { src = e - E0_EDGES; dst = src; }
  int pos = atomicAdd(&cnt[dst], 1);
  if (pos < CAP) slots[dst * CAP + pos] = src;
}

// ======================= fp32 -> bf16 conversion =============================

__global__ void convert_x_kernel(const float* __restrict__ x, ushort* __restrict__ xb) {
  size_t i = ((size_t)blockIdx.x * blockDim.x + threadIdx.x) * 4;
  if (i >= (size_t)NPAD * 512) return;
  if (i < (size_t)N_NODES * 512) {
    float4 v = *(const float4*)(x + i);
    ushort4 o;
    o.x = f2bf(v.x); o.y = f2bf(v.y); o.z = f2bf(v.z); o.w = f2bf(v.w);
    *(ushort4*)(xb + i) = o;
  } else {
    *(ushort4*)(xb + i) = make_ushort4(0, 0, 0, 0);
  }
}

// Bt[m][k] = bf16(W[k][m]); all six weight matrices in one launch (z selects)
__global__ void transpose_all_kernel(
    const float* __restrict__ W1, const float* __restrict__ lW1,
    const float* __restrict__ W2, const float* __restrict__ lW2,
    const float* __restrict__ W3, const float* __restrict__ lW3,
    ushort* __restrict__ Bt1, ushort* __restrict__ Bt2, ushort* __restrict__ Bt3) {
  __shared__ float tile[32][33];
  const int K = 512;
  int z = blockIdx.z;
  const float* W; ushort* B; int M;
  switch (z) {
    case 0:  W = W1;  B = Bt1;              M = 512; break;
    case 1:  W = lW1; B = Bt1 + 512 * 512;  M = 512; break;
    case 2:  W = W2;  B = Bt2;              M = 512; break;
    case 3:  W = lW2; B = Bt2 + 512 * 512;  M = 512; break;
    case 4:  W = W3;  B = Bt3;              M = 384; break;
    default: W = lW3; B = Bt3 + 384 * 512;  M = 64;  break;
  }
  int mb = blockIdx.x * 32, kb = blockIdx.y * 32;
  if (mb >= M) return;
  int tx = threadIdx.x, ty = threadIdx.y;  // 32 x 8
#pragma unroll
  for (int i = 0; i < 32; i += 8)
    tile[ty + i][tx] = W[(size_t)(kb + ty + i) * M + mb + tx];
  __syncthreads();
#pragma unroll
  for (int i = 0; i < 32; i += 8)
    B[(size_t)(mb + ty + i) * K + kb + tx] = f2bf(tile[tx][ty + i]);
}

// ==== bf16 MFMA GEMM (r11, best known): persistent, 128x128, BK=32, ========
// ==== 3-slot LDS ring, ONE barrier/K-step, vmcnt(4)+lgkmcnt(0) drain. =======

template <typename Out1T>
__global__ __launch_bounds__(256, 3) void mfma_gemm_kernel(
    const ushort* __restrict__ A,   // [NPAD][512] bf16
    const ushort* __restrict__ Bt,  // [colpad][512] bf16
    ushort* __restrict__ out0, int ld0, int split,
    Out1T* __restrict__ out1, int ld1, int Mout1, const float* __restrict__ bias1,
    const float* __restrict__ att_sw, const float* __restrict__ att_dw,  // [H][C]
    float* __restrict__ a_sp, float* __restrict__ a_dp,  // [N*H*2] half-parts
    int nheads, int headC,
    int NT, int nwg) {
  const int K = 512;
  __shared__ __attribute__((aligned(16))) ushort As[3][128][32];
  __shared__ __attribute__((aligned(16))) ushort Bs[3][128][32];

  int tid = threadIdx.x, lane = tid & 63, wave = tid >> 6;
  int wrow = (wave >> 1) * 64, wcol = (wave & 1) * 64;

  size_t K2 = (size_t)K * 2;
  int rofs = lane >> 2;
  int gch = (lane & 3) ^ SW(rofs);
  int srow[2];
#pragma unroll
  for (int it = 0; it < 2; ++it) srow[it] = wave * 32 + it * 16;

  int fr = lane & 15, hi = lane >> 4;
  int rch = hi ^ SW(fr);  // read-side swizzled chunk

  char* AsB = (char*)&As[0][0][0];
  char* BsB = (char*)&Bs[0][0][0];

  int q = nwg >> 3, r = nwg & 7;

  for (int w0 = blockIdx.x; w0 < nwg; w0 += gridDim.x) {
    // bijective XCD-chunked swizzle (m204); row-panel-major linearization
    int xcd = w0 & 7, pos = w0 >> 3;
    int wgid = (xcd < r ? xcd * (q + 1) : r * (q + 1) + (xcd - r) * q) + pos;
    int by = wgid / NT, bx = wgid - by * NT;
    int bm = by * 128, bn = bx * 128;

    const char* pA[2];
    const char* pB[2];
#pragma unroll
    for (int it = 0; it < 2; ++it) {
      pA[it] = (const char*)A + (size_t)(bm + srow[it] + rofs) * K2 + gch * 16;
      pB[it] = (const char*)Bt + (size_t)(bn + srow[it] + rofs) * K2 + gch * 16;
    }

    f32x4 acc[4][4] = {};

    // prologue: stage steps 0 and 1 (slots 0,1) -> 8 outstanding loads/wave
#pragma unroll
    for (int s = 0; s < 2; ++s) {
#pragma unroll
      for (int it = 0; it < 2; ++it) {
        GLOAD16(pA[it], AsB + s * 8192 + srow[it] * 64);
        GLOAD16(pB[it], BsB + s * 8192 + srow[it] * 64);
      }
#pragma unroll
      for (int it = 0; it < 2; ++it) { pA[it] += 64; pB[it] += 64; }
    }

    // 16 K-steps; slot k%3, stage (k+2)%3 after the barrier.
    for (int k = 0; k < 16; ++k) {
      if (k + 1 < 16) asm volatile("s_waitcnt vmcnt(4) lgkmcnt(0)" ::: "memory");
      else            asm volatile("s_waitcnt vmcnt(0) lgkmcnt(0)" ::: "memory");
      __builtin_amdgcn_s_barrier();   // step-k ready everywhere; k-1 consumed
      asm volatile("" ::: "memory");
      if (k + 2 < 16) {               // stage step k+2 (overwrites slot of k-1)
        int ss = (k + 2) % 3;
#pragma unroll
        for (int it = 0; it < 2; ++it) {
          GLOAD16(pA[it], AsB + ss * 8192 + srow[it] * 64);
          GLOAD16(pB[it], BsB + ss * 8192 + srow[it] * 64);
        }
#pragma unroll
        for (int it = 0; it < 2; ++it) { pA[it] += 64; pB[it] += 64; }
      }
      {
        int sc = k % 3;
        bf16x8 af[4], bf[4];
#pragma unroll
        for (int i = 0; i < 4; ++i)
          af[i] = *(const bf16x8*)&As[sc][wrow + i * 16 + fr][rch * 8];
#pragma unroll
        for (int j = 0; j < 4; ++j)
          bf[j] = *(const bf16x8*)&Bs[sc][wcol + j * 16 + fr][rch * 8];
#pragma unroll
        for (int i = 0; i < 4; ++i)
#pragma unroll
          for (int j = 0; j < 4; ++j)
            acc[i][j] = __builtin_amdgcn_mfma_f32_16x16x32_bf16(af[i], bf[j], acc[i][j], 0, 0, 0);
      }
      asm volatile("" ::: "memory");
    }

    // tile seam: all waves' step-15 LDS reads done before next prologue stages
    asm volatile("s_waitcnt lgkmcnt(0)" ::: "memory");
    __builtin_amdgcn_s_barrier();
    asm volatile("" ::: "memory");

    // ---- epilogue: C/D layout col=lane&15, row=(lane>>4)*4+reg [m89/m91] ----
    int colg = bn + wcol;            // 64-aligned, wave-uniform
    bool lower = colg < split;
    int g4 = hi << 2;
    int ccol = fr;
#pragma unroll
    for (int i = 0; i < 4; ++i) {
#pragma unroll
      for (int rr = 0; rr < 4; ++rr) {
        int row = bm + wrow + g4 + i * 16 + rr;
        if (row >= N_NODES) continue;
#pragma unroll
        for (int j = 0; j < 4; ++j) {
          int col = colg + j * 16 + ccol;
          float v = acc[i][j][rr];
          if (lower) {
            out0[(size_t)row * ld0 + col] = f2bf(v);
          } else {
            int c1 = col - split;
            if (c1 < Mout1) {
              float b = v + bias1[c1];
              if constexpr (std::is_same<Out1T, ushort>::value)
                out1[(size_t)row * ld1 + c1] = f2bf(b);
              else
                out1[(size_t)row * ld1 + c1] = b;
            }
          }
        }
      }
    }

    // ---- fused attention scores: a_s/a_d = h . att over this wave's 64 cols --
    if (lower) {
      int hd = colg / headC;               // wave-uniform head
      int cb = colg - hd * headC;          // 0 or 64
      int half = (cb >> 6) & 1;
      float ws4[4], wd4[4];
#pragma unroll
      for (int j = 0; j < 4; ++j) {
        int cc = hd * headC + cb + j * 16 + ccol;
        ws4[j] = att_sw[cc];
        wd4[j] = att_dw[cc];
      }
#pragma unroll
      for (int i = 0; i < 4; ++i) {
#pragma unroll
        for (int rr = 0; rr < 4; ++rr) {
          float ps = 0.f, pd = 0.f;
#pragma unroll
          for (int j = 0; j < 4; ++j) { ps += acc[i][j][rr] * ws4[j]; pd += acc[i][j][rr] * wd4[j]; }
#pragma unroll
          for (int o = 1; o < 16; o <<= 1) { ps += __shfl_xor(ps, o); pd += __shfl_xor(pd, o); }
          if ((lane & 15) == 0) {
            int row = bm + wrow + g4 + i * 16 + rr;
            if (row < N_NODES) {
              size_t idx = ((size_t)row * nheads + hd) * 2;
              if (headC == 128) {
                a_sp[idx + half] = ps;
                a_dp[idx + half] = pd;
              } else {
                a_sp[idx] = ps;  a_sp[idx + 1] = 0.f;
                a_dp[idx] = pd;  a_dp[idx + 1] = 0.f;
              }
            }
          }
        }
      }
    }
  }
}

// ======================= fused softmax + gather (layers 1,2) =================
// 128 threads (2 waves). Phase 1: wave w computes softmax for heads 2w,2w+1.
// Phase 2: lane l of wave w owns features 8l..8l+7 for edges j === w (mod 2)
// (16B ushort8 loads, 1KB/edge per wave); combine in LDS; thread t finalizes
// features 4t..4t+3 with skip+bias+ELU.

template <int H, int C>
__global__ __launch_bounds__(128) void gather12_fused(
    const int* __restrict__ cnt, const int* __restrict__ slots,
    const float* __restrict__ a_sp, const float* __restrict__ a_dp,
    const ushort* __restrict__ hbuf, const float* __restrict__ gat_bias,
    const ushort* __restrict__ skip_in, ushort* __restrict__ outbuf) {
  __shared__ float al[H][CAP];
  __shared__ int srcs[CAP];
  __shared__ float part[2][H * C];
  int n = blockIdx.x;
  int t = threadIdx.x, lane = t & 63, w = t >> 6;  // 2 waves
  int deg = min(cnt[n], CAP);

  int sj = 0;
  if (lane < deg) sj = slots[n * CAP + lane];
#pragma unroll
  for (int hh = 0; hh < 2; ++hh) {
    int hd = 2 * w + hh;
    float e = -1e30f;
    if (lane < deg) {
      size_t is = ((size_t)sj * H + hd) * 2;
      size_t id = ((size_t)n * H + hd) * 2;
      float v = a_sp[is] + a_sp[is + 1] + a_dp[id] + a_dp[id + 1];
      e = v > 0.f ? v : 0.2f * v;  // leaky_relu
    }
    float m = e;
#pragma unroll
    for (int o = 32; o > 0; o >>= 1) m = fmaxf(m, __shfl_xor(m, o));
    float ex = (lane < deg) ? expf(e - m) : 0.f;
    float s = ex;
#pragma unroll
    for (int o = 32; o > 0; o >>= 1) s += __shfl_xor(s, o);
    float inv = 1.f / (s + 1e-16f);
    if (lane < deg) al[hd][lane] = ex * inv;
  }
  if (w == 0 && lane < deg) srcs[lane] = sj;
  __syncthreads();

  // phase 2: wave w handles edges j = w, w+2, ...; lane covers 8 features
  int f0 = 8 * lane, hd = lane >> 4;
  float a8[8] = {};
  for (int j = w; j < deg; j += 2) {
    float a = al[hd][j];
    ushort8 hv = *(const ushort8*)(hbuf + (size_t)srcs[j] * (H * C) + f0);
#pragma unroll
    for (int e = 0; e < 8; ++e) a8[e] += a * bf2f(hv[e]);
  }
  *(f32x4*)&part[w][f0] = *(f32x4*)&a8[0];
  *(f32x4*)&part[w][f0 + 4] = *(f32x4*)&a8[4];
  __syncthreads();

  // finalize: thread t -> features 4t..4t+3
  int g0 = 4 * t;
  f32x4 p0 = *(const f32x4*)&part[0][g0];
  f32x4 p1 = *(const f32x4*)&part[1][g0];
  ushort4 sk = *(const ushort4*)(skip_in + (size_t)n * (H * C) + g0);
  float o0 = p0[0] + p1[0] + gat_bias[g0 + 0] + bf2f(sk.x);
  float o1 = p0[1] + p1[1] + gat_bias[g0 + 1] + bf2f(sk.y);
  float o2 = p0[2] + p1[2] + gat_bias[g0 + 2] + bf2f(sk.z);
  float o3 = p0[3] + p1[3] + gat_bias[g0 + 3] + bf2f(sk.w);
  o0 = o0 > 0.f ? o0 : (expf(o0) - 1.f);  // ELU
  o1 = o1 > 0.f ? o1 : (expf(o1) - 1.f);
  o2 = o2 > 0.f ? o2 : (expf(o2) - 1.f);
  o3 = o3 > 0.f ? o3 : (expf(o3) - 1.f);
  ushort4 ov;
  ov.x = f2bf(o0); ov.y = f2bf(o1); ov.z = f2bf(o2); ov.w = f2bf(o3);
  *(ushort4*)(outbuf + (size_t)n * (H * C) + g0) = ov;
}

// ======================= fused softmax + gather (layer 3, mean heads) ========
// 128 threads. Phase 1: softmax for 6 heads (wave w -> heads 3w..3w+2).
// Phase 2: threads t<96: hd=t>>4, c4=(t&15)*4 -> ushort4 load per edge
// (768B/edge contiguous); combine part[6][64]; t<64 writes out.

__global__ __launch_bounds__(128) void gather3_fused(
    const int* __restrict__ cnt, const int* __restrict__ slots,
    const float* __restrict__ a_sp, const float* __restrict__ a_dp,
    const ushort* __restrict__ hbuf /*N x 384*/, const float* __restrict__ b3,
    float* __restrict__ out /*N x 64, holds skip+lb3*/) {
  __shared__ float al[6][CAP];
  __shared__ int srcs[CAP];
  __shared__ float part[6][64];
  int n = blockIdx.x;
  int t = threadIdx.x, lane = t & 63, w = t >> 6;
  int deg = min(cnt[n], CAP);

  int sj = 0;
  if (lane < deg) sj = slots[n * CAP + lane];
#pragma unroll
  for (int hh = 0; hh < 3; ++hh) {
    int hd = 3 * w + hh;
    float e = -1e30f;
    if (lane < deg) {
      size_t is = ((size_t)sj * 6 + hd) * 2;
      size_t id = ((size_t)n * 6 + hd) * 2;
      float v = a_sp[is] + a_sp[is + 1] + a_dp[id] + a_dp[id + 1];
      e = v > 0.f ? v : 0.2f * v;
    }
    float m = e;
#pragma unroll
    for (int o = 32; o > 0; o >>= 1) m = fmaxf(m, __shfl_xor(m, o));
    float ex = (lane < deg) ? expf(e - m) : 0.f;
    float s = ex;
#pragma unroll
    for (int o = 32; o > 0; o >>= 1) s += __shfl_xor(s, o);
    float inv = (1.f / 6.f) / (s + 1e-16f);  // fold mean over heads
    if (lane < deg) al[hd][lane] = ex * inv;
  }
  if (w == 0 && lane < deg) srcs[lane] = sj;
  __syncthreads();

  if (t < 96) {
    int hd = t >> 4, c4 = (t & 15) * 4;
    float a4[4] = {};
    for (int j = 0; j < deg; ++j) {
      float a = al[hd][j];
      ushort4 hv = *(const ushort4*)(hbuf + (size_t)srcs[j] * 384 + hd * 64 + c4);
      a4[0] += a * bf2f(hv.x);
      a4[1] += a * bf2f(hv.y);
      a4[2] += a * bf2f(hv.z);
      a4[3] += a * bf2f(hv.w);
    }
    *(f32x4*)&part[hd][c4] = *(f32x4*)&a4[0];
  }
  __syncthreads();
  if (t < 64) {
    float s = part[0][t] + part[1][t] + part[2][t] +
              part[3][t] + part[4][t] + part[5][t];
    size_t oi = (size_t)n * 64 + t;
    out[oi] += s + b3[t];
  }
}

// ======================= host launch =========================================

extern "C" void kernel_launch(void* const* d_in, const int* in_sizes, int n_in,
                              void* d_out, int out_size, void* d_ws, size_t ws_size,
                              hipStream_t stream) {
  const float* x   = (const float*)d_in[0];
  const int*   ei  = (const int*)d_in[1];
  const float* W1  = (const float*)d_in[2];
  const float* as1 = (const float*)d_in[3];
  const float* ad1 = (const float*)d_in[4];
  const float* b1  = (const float*)d_in[5];
  const float* lW1 = (const float*)d_in[6];
  const float* lb1 = (const float*)d_in[7];
  const float* W2  = (const float*)d_in[8];
  const float* as2 = (const float*)d_in[9];
  const float* ad2 = (const float*)d_in[10];
  const float* b2  = (const float*)d_in[11];
  const float* lW2 = (const float*)d_in[12];
  const float* lb2 = (const float*)d_in[13];
  const float* W3  = (const float*)d_in[14];
  const float* as3 = (const float*)d_in[15];
  const float* ad3 = (const float*)d_in[16];
  const float* b3  = (const float*)d_in[17];
  const float* lW3 = (const float*)d_in[18];
  const float* lb3 = (const float*)d_in[19];
  float* out = (float*)d_out;

  char* ws = (char*)d_ws;
  auto alloc = [&](size_t bytes) -> void* {
    void* p = (void*)ws;
    ws += (bytes + 255) & ~(size_t)255;
    return p;
  };
  ushort* xb    = (ushort*)alloc((size_t)NPAD * 512 * 2);
  ushort* Pb    = (ushort*)alloc((size_t)NPAD * 512 * 2);
  ushort* Qb    = (ushort*)alloc((size_t)NPAD * 512 * 2);
  ushort* skipb = (ushort*)alloc((size_t)N_NODES * 512 * 2);
  ushort* hb    = (ushort*)alloc((size_t)N_NODES * 512 * 2);
  ushort* Bt1   = (ushort*)alloc((size_t)1024 * 512 * 2);
  ushort* Bt2   = (ushort*)alloc((size_t)1024 * 512 * 2);
  ushort* Bt3   = (ushort*)alloc((size_t)512 * 512 * 2);
  float*  a_sp  = (float*)alloc((size_t)N_NODES * 6 * 2 * 4);
  float*  a_dp  = (float*)alloc((size_t)N_NODES * 6 * 2 * 4);
  int*    cnt   = (int*)alloc((size_t)N_NODES * 4);
  int*    slots = (int*)alloc((size_t)N_NODES * CAP * 4);

  // ---- CSR slots ----
  hipMemsetAsync(cnt, 0, N_NODES * sizeof(int), stream);
  fill_csr_kernel<<<(E_TOT + 255) / 256, 256, 0, stream>>>(ei, cnt, slots);

  // ---- conversions / weight transposes ----
  convert_x_kernel<<<((NPAD * 512 / 4) + 255) / 256, 256, 0, stream>>>(x, xb);
  transpose_all_kernel<<<dim3(16, 16, 6), dim3(32, 8), 0, stream>>>(
      W1, lW1, W2, lW2, W3, lW3, Bt1, Bt2, Bt3);

  const int NBY = NPAD / 128;          // 157 row tiles
  const int NWG12 = NBY * 8;           // 1256 tiles (8 col tiles of 128)
  const int NWG3  = NBY * 4;           // 628 tiles  (4 col tiles of 128)
  const int PERSIST = 256 * 3;         // 3 blocks/CU co-resident
  const int G12 = NWG12 < PERSIST ? NWG12 : PERSIST;  // 768
  const int G3  = NWG3  < PERSIST ? NWG3  : PERSIST;  // 628

  // ---- layer 1 ----
  mfma_gemm_kernel<ushort><<<G12, 256, 0, stream>>>(
      xb, Bt1, hb, 512, 512, skipb, 512, 512, lb1, as1, ad1, a_sp, a_dp, 4, 128,
      8, NWG12);
  gather12_fused<4, 128><<<N_NODES, 128, 0, stream>>>(cnt, slots, a_sp, a_dp, hb, b1, skipb, Pb);

  // ---- layer 2 ----
  mfma_gemm_kernel<ushort><<<G12, 256, 0, stream>>>(
      Pb, Bt2, hb, 512, 512, skipb, 512, 512, lb2, as2, ad2, a_sp, a_dp, 4, 128,
      8, NWG12);
  gather12_fused<4, 128><<<N_NODES, 128, 0, stream>>>(cnt, slots, a_sp, a_dp, hb, b2, skipb, Qb);

  // ---- layer 3 ----
  mfma_gemm_kernel<float><<<G3, 256, 0, stream>>>(
      Qb, Bt3, hb, 384, 384, out, 64, 64, lb3, as3, ad3, a_sp, a_dp, 6, 64,
      4, NWG3);
  gather3_fused<<<N_NODES, 128, 0, stream>>>(cnt, slots, a_sp, a_dp, hb, b3, out);
}

// Round 15
// 244.906 us; speedup vs baseline: 1.3270x; 1.0471x over previous
//
#include <hip/hip_runtime.h>
#include <cstddef>
#include <cstdint>
#include <type_traits>

#define N_NODES 20000
#define NPAD 20096            // multiple of 128 for MFMA row tiles
#define E0_EDGES 160000
#define E_TOT (E0_EDGES + N_NODES)
#define CAP 64                // max in-degree slots (Poisson(9); P(>=64) ~ 0)

typedef __bf16 bf16x8 __attribute__((ext_vector_type(8)));
typedef float f32x4 __attribute__((ext_vector_type(4)));
typedef ushort ushort8 __attribute__((ext_vector_type(8)));

__device__ __forceinline__ ushort f2bf(float f) {
  uint32_t u = __float_as_uint(f);
  return (ushort)((u + 0x7FFFu + ((u >> 16) & 1u)) >> 16);  // RNE
}
__device__ __forceinline__ float bf2f(ushort h) {
  return __uint_as_float((uint32_t)h << 16);
}

// chunk swizzle for 64B LDS rows
__device__ __forceinline__ int SW(int r) { return ((r >> 1) & 3) ^ ((r >> 3) & 1); }

// async global->LDS, 16B/lane; LDS dest = wave-uniform base + lane*16
#define GLOAD16(g, l)                                                         \
  __builtin_amdgcn_global_load_lds(                                           \
      (const __attribute__((address_space(1))) void*)(uintptr_t)(g),          \
      (__attribute__((address_space(3))) void*)(uint32_t)(uintptr_t)(l),      \
      16, 0, 0)

// ======================= CSR via fixed-stride slots ==========================

__global__ void fill_csr_kernel(const int* __restrict__ ei, int* __restrict__ cnt,
                                int* __restrict__ slots) {
  int e = blockIdx.x * blockDim.x + threadIdx.x;
  if (e >= E_TOT) return;
  int src, dst;
  if (e < E0_EDGES) { src = ei[e]; dst = ei[E0_EDGES + e]; }
  else              { src = e - E0_EDGES; dst = src; }
  int pos = atomicAdd(&cnt[dst], 1);
  if (pos < CAP) slots[dst * CAP + pos] = src;
}

// ======================= fp32 -> bf16 conversion =============================

__global__ void convert_x_kernel(const float* __restrict__ x, ushort* __restrict__ xb) {
  size_t i = ((size_t)blockIdx.x * blockDim.x + threadIdx.x) * 4;
  if (i >= (size_t)NPAD * 512) return;
  if (i < (size_t)N_NODES * 512) {
    float4 v = *(const float4*)(x + i);
    ushort4 o;
    o.x = f2bf(v.x); o.y = f2bf(v.y); o.z = f2bf(v.z); o.w = f2bf(v.w);
    *(ushort4*)(xb + i) = o;
  } else {
    *(ushort4*)(xb + i) = make_ushort4(0, 0, 0, 0);
  }
}

// Bt[m][k] = bf16(W[k][m]); all six weight matrices in one launch (z selects)
__global__ void transpose_all_kernel(
    const float* __restrict__ W1, const float* __restrict__ lW1,
    const float* __restrict__ W2, const float* __restrict__ lW2,
    const float* __restrict__ W3, const float* __restrict__ lW3,
    ushort* __restrict__ Bt1, ushort* __restrict__ Bt2, ushort* __restrict__ Bt3) {
  __shared__ float tile[32][33];
  const int K = 512;
  int z = blockIdx.z;
  const float* W; ushort* B; int M;
  switch (z) {
    case 0:  W = W1;  B = Bt1;              M = 512; break;
    case 1:  W = lW1; B = Bt1 + 512 * 512;  M = 512; break;
    case 2:  W = W2;  B = Bt2;              M = 512; break;
    case 3:  W = lW2; B = Bt2 + 512 * 512;  M = 512; break;
    case 4:  W = W3;  B = Bt3;              M = 384; break;
    default: W = lW3; B = Bt3 + 384 * 512;  M = 64;  break;
  }
  int mb = blockIdx.x * 32, kb = blockIdx.y * 32;
  if (mb >= M) return;
  int tx = threadIdx.x, ty = threadIdx.y;  // 32 x 8
#pragma unroll
  for (int i = 0; i < 32; i += 8)
    tile[ty + i][tx] = W[(size_t)(kb + ty + i) * M + mb + tx];
  __syncthreads();
#pragma unroll
  for (int i = 0; i < 32; i += 8)
    B[(size_t)(mb + ty + i) * K + kb + tx] = f2bf(tile[tx][ty + i]);
}

// ==== bf16 MFMA GEMM: persistent, 128x128, BK=32, 3-slot ring, 8 WAVES ======
// Wave tile 32x64 (acc[2][4]); 2 gloads/wave/step; steady vmcnt(2);
// launch_bounds(512,6) -> 3 blocks/CU = 24 waves/CU (6/SIMD) for latency
// hiding. ONE barrier per K-step; lgkmcnt(0) drained before every barrier.

template <typename Out1T>
__global__ __launch_bounds__(512, 6) void mfma_gemm_kernel(
    const ushort* __restrict__ A,   // [NPAD][512] bf16
    const ushort* __restrict__ Bt,  // [colpad][512] bf16
    ushort* __restrict__ out0, int ld0, int split,
    Out1T* __restrict__ out1, int ld1, int Mout1, const float* __restrict__ bias1,
    const float* __restrict__ att_sw, const float* __restrict__ att_dw,  // [H][C]
    float* __restrict__ a_sp, float* __restrict__ a_dp,  // [N*H*2] half-parts
    int nheads, int headC,
    int NT, int nwg) {
  const int K = 512;
  __shared__ __attribute__((aligned(16))) ushort As[3][128][32];
  __shared__ __attribute__((aligned(16))) ushort Bs[3][128][32];

  int tid = threadIdx.x, lane = tid & 63, wave = tid >> 6;  // 8 waves
  int wrow = (wave >> 1) * 32, wcol = (wave & 1) * 64;

  size_t K2 = (size_t)K * 2;
  // staging: wave covers tile rows [wave*16, wave*16+16), 1 load each of A,B.
  // lane -> row lane>>2, LDS chunk lane&3; SOURCE chunk = (lane&3) ^ SW(row)
  int rofs = lane >> 2;
  int gch = (lane & 3) ^ SW(rofs);
  int srow = wave * 16;

  int fr = lane & 15, hi = lane >> 4;
  int rch = hi ^ SW(fr);  // read-side swizzled chunk

  char* AsB = (char*)&As[0][0][0];
  char* BsB = (char*)&Bs[0][0][0];

  int q = nwg >> 3, r = nwg & 7;

  for (int w0 = blockIdx.x; w0 < nwg; w0 += gridDim.x) {
    // bijective XCD-chunked swizzle (m204); row-panel-major linearization
    int xcd = w0 & 7, pos = w0 >> 3;
    int wgid = (xcd < r ? xcd * (q + 1) : r * (q + 1) + (xcd - r) * q) + pos;
    int by = wgid / NT, bx = wgid - by * NT;
    int bm = by * 128, bn = bx * 128;

    const char* pA = (const char*)A + (size_t)(bm + srow + rofs) * K2 + gch * 16;
    const char* pB = (const char*)Bt + (size_t)(bn + srow + rofs) * K2 + gch * 16;

    f32x4 acc[2][4] = {};

    // prologue: stage steps 0 and 1 (slots 0,1) -> 4 outstanding loads/wave
#pragma unroll
    for (int s = 0; s < 2; ++s) {
      GLOAD16(pA, AsB + s * 8192 + srow * 64);
      GLOAD16(pB, BsB + s * 8192 + srow * 64);
      pA += 64; pB += 64;
    }

    // 16 K-steps; slot k%3, stage (k+2)%3 after the barrier.
    for (int k = 0; k < 16; ++k) {
      if (k + 1 < 16) asm volatile("s_waitcnt vmcnt(2) lgkmcnt(0)" ::: "memory");
      else            asm volatile("s_waitcnt vmcnt(0) lgkmcnt(0)" ::: "memory");
      __builtin_amdgcn_s_barrier();   // step-k ready everywhere; k-1 consumed
      asm volatile("" ::: "memory");
      if (k + 2 < 16) {               // stage step k+2 (overwrites slot of k-1)
        int ss = (k + 2) % 3;
        GLOAD16(pA, AsB + ss * 8192 + srow * 64);
        GLOAD16(pB, BsB + ss * 8192 + srow * 64);
        pA += 64; pB += 64;
      }
      {
        int sc = k % 3;
        bf16x8 af[2], bf[4];
#pragma unroll
        for (int i = 0; i < 2; ++i)
          af[i] = *(const bf16x8*)&As[sc][wrow + i * 16 + fr][rch * 8];
#pragma unroll
        for (int j = 0; j < 4; ++j)
          bf[j] = *(const bf16x8*)&Bs[sc][wcol + j * 16 + fr][rch * 8];
#pragma unroll
        for (int i = 0; i < 2; ++i)
#pragma unroll
          for (int j = 0; j < 4; ++j)
            acc[i][j] = __builtin_amdgcn_mfma_f32_16x16x32_bf16(af[i], bf[j], acc[i][j], 0, 0, 0);
      }
      asm volatile("" ::: "memory");
    }

    // tile seam: all waves' step-15 LDS reads done before next prologue stages
    asm volatile("s_waitcnt lgkmcnt(0)" ::: "memory");
    __builtin_amdgcn_s_barrier();
    asm volatile("" ::: "memory");

    // ---- epilogue: C/D layout col=lane&15, row=(lane>>4)*4+reg [m89/m91] ----
    int colg = bn + wcol;            // 64-aligned, wave-uniform
    bool lower = colg < split;       // split 128-aligned vs bn; wcol<128 -> ok
    int g4 = hi << 2;
    int ccol = fr;
#pragma unroll
    for (int i = 0; i < 2; ++i) {
#pragma unroll
      for (int rr = 0; rr < 4; ++rr) {
        int row = bm + wrow + g4 + i * 16 + rr;
        if (row >= N_NODES) continue;
#pragma unroll
        for (int j = 0; j < 4; ++j) {
          int col = colg + j * 16 + ccol;
          float v = acc[i][j][rr];
          if (lower) {
            out0[(size_t)row * ld0 + col] = f2bf(v);
          } else {
            int c1 = col - split;
            if (c1 < Mout1) {
              float b = v + bias1[c1];
              if constexpr (std::is_same<Out1T, ushort>::value)
                out1[(size_t)row * ld1 + c1] = f2bf(b);
              else
                out1[(size_t)row * ld1 + c1] = b;
            }
          }
        }
      }
    }

    // ---- fused attention scores: a_s/a_d = h . att over this wave's 64 cols --
    if (lower) {
      int hd = colg / headC;               // wave-uniform head
      int cb = colg - hd * headC;          // 0 or 64
      int half = (cb >> 6) & 1;
      float ws4[4], wd4[4];
#pragma unroll
      for (int j = 0; j < 4; ++j) {
        int cc = hd * headC + cb + j * 16 + ccol;
        ws4[j] = att_sw[cc];
        wd4[j] = att_dw[cc];
      }
#pragma unroll
      for (int i = 0; i < 2; ++i) {
#pragma unroll
        for (int rr = 0; rr < 4; ++rr) {
          float ps = 0.f, pd = 0.f;
#pragma unroll
          for (int j = 0; j < 4; ++j) { ps += acc[i][j][rr] * ws4[j]; pd += acc[i][j][rr] * wd4[j]; }
#pragma unroll
          for (int o = 1; o < 16; o <<= 1) { ps += __shfl_xor(ps, o); pd += __shfl_xor(pd, o); }
          if ((lane & 15) == 0) {
            int row = bm + wrow + g4 + i * 16 + rr;
            if (row < N_NODES) {
              size_t idx = ((size_t)row * nheads + hd) * 2;
              if (headC == 128) {
                a_sp[idx + half] = ps;
                a_dp[idx + half] = pd;
              } else {
                a_sp[idx] = ps;  a_sp[idx + 1] = 0.f;
                a_dp[idx] = pd;  a_dp[idx + 1] = 0.f;
              }
            }
          }
        }
      }
    }
  }
}

// ======================= fused softmax + gather (layers 1,2) =================
// 256 threads (4 waves). Phase 1: wave w computes softmax for head w.
// Phase 2: wave w handles edges j === w (mod 4); lane covers 8 features
// (16B ushort8 loads); combine part[4][512] in LDS; thread t finalizes
// features 2t, 2t+1 with skip+bias+ELU.

template <int H, int C>
__global__ __launch_bounds__(256) void gather12_fused(
    const int* __restrict__ cnt, const int* __restrict__ slots,
    const float* __restrict__ a_sp, const float* __restrict__ a_dp,
    const ushort* __restrict__ hbuf, const float* __restrict__ gat_bias,
    const ushort* __restrict__ skip_in, ushort* __restrict__ outbuf) {
  __shared__ float al[H][CAP];
  __shared__ int srcs[CAP];
  __shared__ float part[4][H * C];
  int n = blockIdx.x;
  int t = threadIdx.x, lane = t & 63, w = t >> 6;  // 4 waves
  int deg = min(cnt[n], CAP);

  int sj = 0;
  if (lane < deg) sj = slots[n * CAP + lane];
  {
    int hd = w;  // wave w -> head w
    float e = -1e30f;
    if (lane < deg) {
      size_t is = ((size_t)sj * H + hd) * 2;
      size_t id = ((size_t)n * H + hd) * 2;
      float v = a_sp[is] + a_sp[is + 1] + a_dp[id] + a_dp[id + 1];
      e = v > 0.f ? v : 0.2f * v;  // leaky_relu
    }
    float m = e;
#pragma unroll
    for (int o = 32; o > 0; o >>= 1) m = fmaxf(m, __shfl_xor(m, o));
    float ex = (lane < deg) ? expf(e - m) : 0.f;
    float s = ex;
#pragma unroll
    for (int o = 32; o > 0; o >>= 1) s += __shfl_xor(s, o);
    float inv = 1.f / (s + 1e-16f);
    if (lane < deg) al[hd][lane] = ex * inv;
  }
  if (w == 0 && lane < deg) srcs[lane] = sj;
  __syncthreads();

  // phase 2: wave w handles edges j = w, w+4, ...; lane covers 8 features
  int f0 = 8 * lane, hd = lane >> 4;
  float a8[8] = {};
  for (int j = w; j < deg; j += 4) {
    float a = al[hd][j];
    ushort8 hv = *(const ushort8*)(hbuf + (size_t)srcs[j] * (H * C) + f0);
#pragma unroll
    for (int e = 0; e < 8; ++e) a8[e] += a * bf2f(hv[e]);
  }
  *(f32x4*)&part[w][f0] = *(f32x4*)&a8[0];
  *(f32x4*)&part[w][f0 + 4] = *(f32x4*)&a8[4];
  __syncthreads();

  // finalize: thread t -> features 2t, 2t+1
  int g0 = 2 * t;
  float s0 = part[0][g0] + part[1][g0] + part[2][g0] + part[3][g0];
  float s1 = part[0][g0 + 1] + part[1][g0 + 1] + part[2][g0 + 1] + part[3][g0 + 1];
  uint32_t sk = *(const uint32_t*)(skip_in + (size_t)n * (H * C) + g0);
  float o0 = s0 + gat_bias[g0 + 0] + bf2f((ushort)(sk & 0xffffu));
  float o1 = s1 + gat_bias[g0 + 1] + bf2f((ushort)(sk >> 16));
  o0 = o0 > 0.f ? o0 : (expf(o0) - 1.f);  // ELU
  o1 = o1 > 0.f ? o1 : (expf(o1) - 1.f);
  uint32_t ov = (uint32_t)f2bf(o0) | ((uint32_t)f2bf(o1) << 16);
  *(uint32_t*)(outbuf + (size_t)n * (H * C) + g0) = ov;
}

// ======================= fused softmax + gather (layer 3, mean heads) ========
// 128 threads. Phase 1: softmax for 6 heads (wave w -> heads 3w..3w+2).
// Phase 2: threads t<96: hd=t>>4, c4=(t&15)*4 -> ushort4 load per edge
// (768B/edge contiguous); combine part[6][64]; t<64 writes out.

__global__ __launch_bounds__(128) void gather3_fused(
    const int* __restrict__ cnt, const int* __restrict__ slots,
    const float* __restrict__ a_sp, const float* __restrict__ a_dp,
    const ushort* __restrict__ hbuf /*N x 384*/, const float* __restrict__ b3,
    float* __restrict__ out /*N x 64, holds skip+lb3*/) {
  __shared__ float al[6][CAP];
  __shared__ int srcs[CAP];
  __shared__ float part[6][64];
  int n = blockIdx.x;
  int t = threadIdx.x, lane = t & 63, w = t >> 6;
  int deg = min(cnt[n], CAP);

  int sj = 0;
  if (lane < deg) sj = slots[n * CAP + lane];
#pragma unroll
  for (int hh = 0; hh < 3; ++hh) {
    int hd = 3 * w + hh;
    float e = -1e30f;
    if (lane < deg) {
      size_t is = ((size_t)sj * 6 + hd) * 2;
      size_t id = ((size_t)n * 6 + hd) * 2;
      float v = a_sp[is] + a_sp[is + 1] + a_dp[id] + a_dp[id + 1];
      e = v > 0.f ? v : 0.2f * v;
    }
    float m = e;
#pragma unroll
    for (int o = 32; o > 0; o >>= 1) m = fmaxf(m, __shfl_xor(m, o));
    float ex = (lane < deg) ? expf(e - m) : 0.f;
    float s = ex;
#pragma unroll
    for (int o = 32; o > 0; o >>= 1) s += __shfl_xor(s, o);
    float inv = (1.f / 6.f) / (s + 1e-16f);  // fold mean over heads
    if (lane < deg) al[hd][lane] = ex * inv;
  }
  if (w == 0 && lane < deg) srcs[lane] = sj;
  __syncthreads();

  if (t < 96) {
    int hd = t >> 4, c4 = (t & 15) * 4;
    float a4[4] = {};
    for (int j = 0; j < deg; ++j) {
      float a = al[hd][j];
      ushort4 hv = *(const ushort4*)(hbuf + (size_t)srcs[j] * 384 + hd * 64 + c4);
      a4[0] += a * bf2f(hv.x);
      a4[1] += a * bf2f(hv.y);
      a4[2] += a * bf2f(hv.z);
      a4[3] += a * bf2f(hv.w);
    }
    *(f32x4*)&part[hd][c4] = *(f32x4*)&a4[0];
  }
  __syncthreads();
  if (t < 64) {
    float s = part[0][t] + part[1][t] + part[2][t] +
              part[3][t] + part[4][t] + part[5][t];
    size_t oi = (size_t)n * 64 + t;
    out[oi] += s + b3[t];
  }
}

// ======================= host launch =========================================

extern "C" void kernel_launch(void* const* d_in, const int* in_sizes, int n_in,
                              void* d_out, int out_size, void* d_ws, size_t ws_size,
                              hipStream_t stream) {
  const float* x   = (const float*)d_in[0];
  const int*   ei  = (const int*)d_in[1];
  const float* W1  = (const float*)d_in[2];
  const float* as1 = (const float*)d_in[3];
  const float* ad1 = (const float*)d_in[4];
  const float* b1  = (const float*)d_in[5];
  const float* lW1 = (const float*)d_in[6];
  const float* lb1 = (const float*)d_in[7];
  const float* W2  = (const float*)d_in[8];
  const float* as2 = (const float*)d_in[9];
  const float* ad2 = (const float*)d_in[10];
  const float* b2  = (const float*)d_in[11];
  const float* lW2 = (const float*)d_in[12];
  const float* lb2 = (const float*)d_in[13];
  const float* W3  = (const float*)d_in[14];
  const float* as3 = (const float*)d_in[15];
  const float* ad3 = (const float*)d_in[16];
  const float* b3  = (const float*)d_in[17];
  const float* lW3 = (const float*)d_in[18];
  const float* lb3 = (const float*)d_in[19];
  float* out = (float*)d_out;

  char* ws = (char*)d_ws;
  auto alloc = [&](size_t bytes) -> void* {
    void* p = (void*)ws;
    ws += (bytes + 255) & ~(size_t)255;
    return p;
  };
  ushort* xb    = (ushort*)alloc((size_t)NPAD * 512 * 2);
  ushort* Pb    = (ushort*)alloc((size_t)NPAD * 512 * 2);
  ushort* Qb    = (ushort*)alloc((size_t)NPAD * 512 * 2);
  ushort* skipb = (ushort*)alloc((size_t)N_NODES * 512 * 2);
  ushort* hb    = (ushort*)alloc((size_t)N_NODES * 512 * 2);
  ushort* Bt1   = (ushort*)alloc((size_t)1024 * 512 * 2);
  ushort* Bt2   = (ushort*)alloc((size_t)1024 * 512 * 2);
  ushort* Bt3   = (ushort*)alloc((size_t)512 * 512 * 2);
  float*  a_sp  = (float*)alloc((size_t)N_NODES * 6 * 2 * 4);
  float*  a_dp  = (float*)alloc((size_t)N_NODES * 6 * 2 * 4);
  int*    cnt   = (int*)alloc((size_t)N_NODES * 4);
  int*    slots = (int*)alloc((size_t)N_NODES * CAP * 4);

  // ---- CSR slots ----
  hipMemsetAsync(cnt, 0, N_NODES * sizeof(int), stream);
  fill_csr_kernel<<<(E_TOT + 255) / 256, 256, 0, stream>>>(ei, cnt, slots);

  // ---- conversions / weight transposes ----
  convert_x_kernel<<<((NPAD * 512 / 4) + 255) / 256, 256, 0, stream>>>(x, xb);
  transpose_all_kernel<<<dim3(16, 16, 6), dim3(32, 8), 0, stream>>>(
      W1, lW1, W2, lW2, W3, lW3, Bt1, Bt2, Bt3);

  const int NBY = NPAD / 128;          // 157 row tiles
  const int NWG12 = NBY * 8;           // 1256 tiles (8 col tiles of 128)
  const int NWG3  = NBY * 4;           // 628 tiles  (4 col tiles of 128)
  const int PERSIST = 256 * 3;         // 3 blocks/CU co-resident (512 thr)
  const int G12 = NWG12 < PERSIST ? NWG12 : PERSIST;  // 768
  const int G3  = NWG3  < PERSIST ? NWG3  : PERSIST;  // 628

  // ---- layer 1 ----
  mfma_gemm_kernel<ushort><<<G12, 512, 0, stream>>>(
      xb, Bt1, hb, 512, 512, skipb, 512, 512, lb1, as1, ad1, a_sp, a_dp, 4, 128,
      8, NWG12);
  gather12_fused<4, 128><<<N_NODES, 256, 0, stream>>>(cnt, slots, a_sp, a_dp, hb, b1, skipb, Pb);

  // ---- layer 2 ----
  mfma_gemm_kernel<ushort><<<G12, 512, 0, stream>>>(
      Pb, Bt2, hb, 512, 512, skipb, 512, 512, lb2, as2, ad2, a_sp, a_dp, 4, 128,
      8, NWG12);
  gather12_fused<4, 128><<<N_NODES, 256, 0, stream>>>(cnt, slots, a_sp, a_dp, hb, b2, skipb, Qb);

  // ---- layer 3 ----
  mfma_gemm_kernel<float><<<G3, 512, 0, stream>>>(
      Qb, Bt3, hb, 384, 384, out, 64, 64, lb3, as3, ad3, a_sp, a_dp, 6, 64,
      4, NWG3);
  gather3_fused<<<N_NODES, 128, 0, stream>>>(cnt, slots, a_sp, a_dp, hb, b3, out);
}